// Round 1
// baseline (84195.673 us; speedup 1.0000x reference)
//
#include <hip/hip_runtime.h>
#include <math.h>

#define Tn 64
#define Bn 32
#define INn 64
#define Nn 512
#define WDn 64
#define Rn 4
#define Hn 256
#define G4H 1024
#define OUTn 64
#define IFn 471
#define CTRLn 320
#define CLIPV 20.0f
#define EPSV 1e-6f

#define NBLK 256
#define NTHR 512

#define OFF_RKEY 0
#define OFF_RSTR 256
#define OFF_WKEY 260
#define OFF_WSTR 324
#define OFF_ERASE 325
#define OFF_WVEC 389
#define OFF_FREE 453
#define OFF_AG 457
#define OFF_WG 458
#define OFF_MODES 459

// ---------------- persistent device state ----------------
__device__ float S_h[Bn][Hn];
__device__ float S_c[Bn][Hn];
__device__ float S_mem[Bn][Nn][WDn];
__device__ float S_rw[Bn][Rn][Nn];
__device__ float S_ww[Bn][Nn];
__device__ float S_link[Bn][Nn][Nn];          // 33.5 MB
__device__ float S_prec[2][Bn][Nn];
__device__ float S_usage[Bn][Nn];
__device__ float S_reads[Bn][Rn][WDn];
__device__ float S_itf[Bn][IFn];
__device__ float S_fw[Bn][Rn][Nn];
__device__ float S_bwp[Bn][8][Rn][Nn];        // per-chunk bw partials (deterministic)
__device__ float S_sumww[Bn];
__device__ unsigned int g_bar[2][8][32];      // [arrive/release][group][pad]

// ---------------- helpers ----------------
__device__ __forceinline__ float sigm(float x){ return 1.f/(1.f+expf(-x)); }
__device__ __forceinline__ float clipv(float x){ return fminf(fmaxf(x,-CLIPV),CLIPV); }
__device__ __forceinline__ float oneplusf(float x){
  float sp = (x > 0.f) ? (x + log1pf(expf(-x))) : log1pf(expf(x));
  return 1.f + sp;
}
__device__ __forceinline__ float wredsum(float v){
  #pragma unroll
  for (int o=32;o>0;o>>=1) v += __shfl_xor(v,o,64);
  return v;
}
__device__ __forceinline__ float bredsum(float v, volatile float* scr){
  v = wredsum(v);
  if ((threadIdx.x & 63) == 0) scr[threadIdx.x >> 6] = v;
  __syncthreads();
  float s = scr[0];
  #pragma unroll
  for (int i=1;i<8;i++) s += scr[i];
  __syncthreads();
  return s;
}
__device__ __forceinline__ float bredmax(float v, volatile float* scr){
  #pragma unroll
  for (int o=32;o>0;o>>=1) v = fmaxf(v,__shfl_xor(v,o,64));
  if ((threadIdx.x & 63) == 0) scr[threadIdx.x >> 6] = v;
  __syncthreads();
  float m = scr[0];
  #pragma unroll
  for (int i=1;i<8;i++) m = fmaxf(m, scr[i]);
  __syncthreads();
  return m;
}

// group barrier: 32 blocks per group, monotonic counter, agent-scope
__device__ __forceinline__ void groupbar(int grp, unsigned int* bark){
  __syncthreads();
  ++(*bark);
  if (threadIdx.x == 0){
    unsigned int k = *bark;
    unsigned int old = __hip_atomic_fetch_add(&g_bar[0][grp][0], 1u,
                        __ATOMIC_ACQ_REL, __HIP_MEMORY_SCOPE_AGENT);
    if (old == k*32u - 1u){
      __hip_atomic_store(&g_bar[1][grp][0], k,
                        __ATOMIC_RELEASE, __HIP_MEMORY_SCOPE_AGENT);
    } else {
      unsigned int v;
      do {
        __builtin_amdgcn_s_sleep(2);
        v = __hip_atomic_load(&g_bar[1][grp][0],
                        __ATOMIC_ACQUIRE, __HIP_MEMORY_SCOPE_AGENT);
      } while (v < k);
    }
  }
  __syncthreads();
}

// ---------------- shared mem layouts ----------------
struct ShA {
  float ctrl[CTRLn];
  float hold[Hn];
  float hc[Hn];
  float itf[IFn];
  float gpart[4][Hn];
  unsigned long long keys[Nn];
  float cp[Nn];
  float alloc[Nn];
  float sim[Nn];
  float wkey[WDn];
  float red[8];
};
struct ShB {
  float ww[Nn];
  float prec[Nn];
  float rw[Rn][Nn];
  float bwp4[4][Rn][Nn];
};
struct ShC {
  float ww[Nn];
  float er[WDn];
  float wvv[WDn];
  float rk[Rn][WDn];
  float beta[Rn];
  float kn[Rn];
  float modes[Rn][4];
  float fw[Rn][Nn];
  float bw[Rn][Nn];
  float sim[Rn][Nn];
  float tile[64][65];
  float part[8][Rn][WDn];
  float vin[512];
  float red[8];
};
union ShU { ShA a; ShB b; ShC c; };

extern "C" __global__ void dnc_init_kernel(){
  int i = threadIdx.x;
  if (i < 512) ((unsigned int*)g_bar)[i] = 0u;
}

extern "C" __global__ void __launch_bounds__(NTHR, 2)
dnc_main_kernel(const float* __restrict__ xin,
                const float* __restrict__ Wx, const float* __restrict__ Wh,
                const float* __restrict__ b_lstm,
                const float* __restrict__ W_if, const float* __restrict__ b_if,
                const float* __restrict__ W_out, const float* __restrict__ b_out,
                float* __restrict__ outp)
{
  __shared__ ShU sh;
  const int tid = threadIdx.x;
  const int lane = tid & 63;
  const int wvi = tid >> 6;
  const int bid = blockIdx.x;
  const int grp = bid & 7;     // group ~ XCD (heuristic; correctness independent)
  const int slot = bid >> 3;   // 0..31 within group
  unsigned int bark = 0u;

  // ---- init: zero this group's state ----
  {
    const int b1 = grp + 8*(slot & 3);  // link owner batch
    const int ch = slot >> 2;
    float* lp = &S_link[b1][ch*64][0];
    for (int k = tid; k < 64*Nn; k += NTHR) lp[k] = 0.f;
    if (slot < 4){
      const int b = grp + 8*slot;
      float* mp = &S_mem[b][0][0];
      for (int k = tid; k < Nn*WDn; k += NTHR) mp[k] = 0.f;
      for (int k = tid; k < Rn*Nn; k += NTHR) ((float*)S_rw[b])[k] = 0.f;
      for (int k = tid; k < Nn; k += NTHR){
        S_ww[b][k]=0.f; S_prec[0][b][k]=0.f; S_prec[1][b][k]=0.f; S_usage[b][k]=0.f;
      }
      for (int k = tid; k < Rn*WDn; k += NTHR) ((float*)S_reads[b])[k] = 0.f;
      for (int k = tid; k < Hn; k += NTHR){ S_h[b][k]=0.f; S_c[b][k]=0.f; }
    }
  }
  groupbar(grp, &bark);

  for (int t = 0; t < Tn; ++t){
    // ================= Phase A : controller + interface + alloc + wc + ww =================
    if (slot < 4){
      const int b = grp + 8*slot;
      // stage ctrl_in = [x_t, reads_prev], h_prev
      for (int k=tid;k<INn;k+=NTHR) sh.a.ctrl[k] = xin[((size_t)t*Bn+b)*INn + k];
      for (int k=tid;k<Rn*WDn;k+=NTHR) sh.a.ctrl[INn+k] = S_reads[b][k>>6][k&63];
      for (int k=tid;k<Hn;k+=NTHR) sh.a.hold[k] = S_h[b][k];
      __syncthreads();
      // gates: low half -> Wx part (+bias), high half -> Wh part
      float g0=0.f,g1=0.f,g2=0.f,g3=0.f;
      if (tid < Hn){
        int h = tid;
        g0=b_lstm[h]; g1=b_lstm[Hn+h]; g2=b_lstm[2*Hn+h]; g3=b_lstm[3*Hn+h];
        for (int k=0;k<CTRLn;k++){
          float cv = sh.a.ctrl[k];
          const float* wr = Wx + (size_t)k*G4H;
          g0 += cv*wr[h]; g1 += cv*wr[Hn+h]; g2 += cv*wr[2*Hn+h]; g3 += cv*wr[3*Hn+h];
        }
      } else {
        int h = tid - Hn;
        for (int k=0;k<Hn;k++){
          float hv = sh.a.hold[k];
          const float* wr = Wh + (size_t)k*G4H;
          g0 += hv*wr[h]; g1 += hv*wr[Hn+h]; g2 += hv*wr[2*Hn+h]; g3 += hv*wr[3*Hn+h];
        }
        sh.a.gpart[0][h]=g0; sh.a.gpart[1][h]=g1; sh.a.gpart[2][h]=g2; sh.a.gpart[3][h]=g3;
      }
      __syncthreads();
      if (tid < Hn){
        int h = tid;
        g0 += sh.a.gpart[0][h]; g1 += sh.a.gpart[1][h]; g2 += sh.a.gpart[2][h]; g3 += sh.a.gpart[3][h];
        float cold = S_c[b][h];
        float cn = sigm(g1)*cold + sigm(g0)*tanhf(g2);
        float hn = sigm(g3)*tanhf(cn);
        float hcv = clipv(hn), ccv = clipv(cn);
        S_h[b][h]=hcv; S_c[b][h]=ccv; sh.a.hc[h]=hcv;
      }
      __syncthreads();
      // itf = hc @ W_if + b_if
      if (tid < IFn){
        float acc = b_if[tid];
        for (int k=0;k<Hn;k++) acc += sh.a.hc[k]*W_if[(size_t)k*IFn + tid];
        S_itf[b][tid]=acc; sh.a.itf[tid]=acc;
      }
      __syncthreads();
      // usage update + sort keys
      {
        float fg0=sigm(sh.a.itf[OFF_FREE+0]), fg1=sigm(sh.a.itf[OFF_FREE+1]);
        float fg2=sigm(sh.a.itf[OFF_FREE+2]), fg3=sigm(sh.a.itf[OFF_FREE+3]);
        int n = tid;
        float uu = S_usage[b][n], wwp = S_ww[b][n];
        float u = uu + (1.f-uu)*wwp;
        float psi = (1.f - fg0*S_rw[b][0][n])*(1.f - fg1*S_rw[b][1][n])
                  * (1.f - fg2*S_rw[b][2][n])*(1.f - fg3*S_rw[b][3][n]);
        float un = u*psi;
        S_usage[b][n] = un;
        float v = EPSV + (1.f-EPSV)*un;                 // > 0 always
        sh.a.keys[n] = ((unsigned long long)__float_as_uint(v) << 32) | (unsigned)n;
      }
      __syncthreads();
      // stable ascending bitonic sort (value, then index) on packed u64
      for (int k=2;k<=Nn;k<<=1){
        for (int j=k>>1;j>0;j>>=1){
          int i = tid, l = i ^ j;
          if (l > i){
            unsigned long long A = sh.a.keys[i], Bk = sh.a.keys[l];
            bool asc = ((i & k) == 0);
            if ((A > Bk) == asc){ sh.a.keys[i]=Bk; sh.a.keys[l]=A; }
          }
          __syncthreads();
        }
      }
      // inclusive cumprod scan of sorted usage
      sh.a.cp[tid] = __uint_as_float((unsigned)(sh.a.keys[tid]>>32));
      __syncthreads();
      for (int d=1; d<Nn; d<<=1){
        float v = sh.a.cp[tid];
        float m = (tid>=d) ? sh.a.cp[tid-d] : 1.f;
        __syncthreads();
        sh.a.cp[tid] = v*m;
        __syncthreads();
      }
      {
        float suv = __uint_as_float((unsigned)(sh.a.keys[tid]>>32));
        float excl = (tid==0)?1.f:sh.a.cp[tid-1];
        float a = (1.f - suv)*excl;
        int orig = (int)(sh.a.keys[tid] & 0xFFFFFFFFull);
        sh.a.alloc[orig] = a;
      }
      if (tid < WDn) sh.a.wkey[tid] = sh.a.itf[OFF_WKEY+tid];
      __syncthreads();
      // write content sims (wave per 64 rows)
      {
        float kv = sh.a.wkey[lane];
        float kn = sqrtf(wredsum(kv*kv));
        float beta = oneplusf(sh.a.itf[OFF_WSTR]);
        for (int nn=0;nn<64;nn++){
          int n = wvi*64+nn;
          float m = S_mem[b][n][lane];
          float dot = wredsum(m*kv);
          float nr  = wredsum(m*m);
          if (lane==0) sh.a.sim[n] = beta * dot / (kn*sqrtf(nr) + EPSV);
        }
      }
      __syncthreads();
      // softmax over N
      {
        float v = sh.a.sim[tid];
        float mx = bredmax(v, sh.a.red);
        float e = expf(v - mx);
        float ssum = bredsum(e, sh.a.red);
        sh.a.sim[tid] = e/ssum;
      }
      __syncthreads();
      // ww + sum(ww)
      {
        float ag = sigm(sh.a.itf[OFF_AG]);
        float wg = sigm(sh.a.itf[OFF_WG]);
        float wwv = wg*(ag*sh.a.alloc[tid] + (1.f-ag)*sh.a.sim[tid]);
        S_ww[b][tid] = wwv;
        float ssum = bredsum(wwv, sh.a.red);
        if (tid==0) S_sumww[b] = ssum;
      }
    }
    groupbar(grp, &bark);

    // ================= Phase B : link update + fw/bw + prec =================
    {
      const int b = grp + 8*(slot & 3);
      const int ch = slot >> 2;
      const int i0 = ch*64;
      sh.b.ww[tid]   = S_ww[b][tid];
      sh.b.prec[tid] = S_prec[t&1][b][tid];
      for (int k=tid;k<Rn*Nn;k+=NTHR) ((float*)sh.b.rw)[k] = ((const float*)S_rw[b])[k];
      __syncthreads();
      float sumww = S_sumww[b];
      float wj[8], pj[8], rj0[8], rj1[8], rj2[8], rj3[8];
      #pragma unroll
      for (int jj=0;jj<8;jj++){
        int j = jj*64+lane;
        wj[jj]=sh.b.ww[j]; pj[jj]=sh.b.prec[j];
        rj0[jj]=sh.b.rw[0][j]; rj1[jj]=sh.b.rw[1][j]; rj2[jj]=sh.b.rw[2][j]; rj3[jj]=sh.b.rw[3][j];
      }
      float b0[8]={0,0,0,0,0,0,0,0}, b1[8]={0,0,0,0,0,0,0,0};
      float b2[8]={0,0,0,0,0,0,0,0}, b3[8]={0,0,0,0,0,0,0,0};
      for (int rr=0;rr<8;rr++){
        int i = i0 + wvi*8 + rr;
        float wi = sh.b.ww[i];
        float ci = 1.f - wi;
        float ri0=sh.b.rw[0][i], ri1=sh.b.rw[1][i], ri2=sh.b.rw[2][i], ri3=sh.b.rw[3][i];
        float f0=0.f,f1=0.f,f2=0.f,f3=0.f;
        float* lrow = &S_link[b][i][0];
        #pragma unroll
        for (int jj=0;jj<8;jj++){
          int j = jj*64+lane;
          float L = lrow[j];
          float Ln = (ci - wj[jj])*L + wi*pj[jj];
          Ln = (j==i) ? 0.f : Ln;
          lrow[j] = Ln;
          f0 += Ln*rj0[jj]; f1 += Ln*rj1[jj]; f2 += Ln*rj2[jj]; f3 += Ln*rj3[jj];
          b0[jj] += Ln*ri0; b1[jj] += Ln*ri1; b2[jj] += Ln*ri2; b3[jj] += Ln*ri3;
        }
        f0=wredsum(f0); f1=wredsum(f1); f2=wredsum(f2); f3=wredsum(f3);
        if (lane==0){ S_fw[b][0][i]=f0; S_fw[b][1][i]=f1; S_fw[b][2][i]=f2; S_fw[b][3][i]=f3; }
      }
      // deterministic cross-wave bw reduce: waves 0-3 write, 4-7 add, then 4-way sum
      if (wvi < 4){
        #pragma unroll
        for (int jj=0;jj<8;jj++){
          int j = jj*64+lane;
          sh.b.bwp4[wvi][0][j]=b0[jj]; sh.b.bwp4[wvi][1][j]=b1[jj];
          sh.b.bwp4[wvi][2][j]=b2[jj]; sh.b.bwp4[wvi][3][j]=b3[jj];
        }
      }
      __syncthreads();
      if (wvi >= 4){
        int v = wvi-4;
        #pragma unroll
        for (int jj=0;jj<8;jj++){
          int j = jj*64+lane;
          sh.b.bwp4[v][0][j]+=b0[jj]; sh.b.bwp4[v][1][j]+=b1[jj];
          sh.b.bwp4[v][2][j]+=b2[jj]; sh.b.bwp4[v][3][j]+=b3[jj];
        }
      }
      __syncthreads();
      for (int k=tid;k<Rn*Nn;k+=NTHR){
        float s = ((float*)sh.b.bwp4[0])[k] + ((float*)sh.b.bwp4[1])[k]
                + ((float*)sh.b.bwp4[2])[k] + ((float*)sh.b.bwp4[3])[k];
        ((float*)S_bwp[b][ch])[k] = s;
      }
      if (tid < 64){
        int j = i0 + tid;
        S_prec[(t&1)^1][b][j] = (1.f - sumww)*sh.b.prec[j] + sh.b.ww[j];
      }
    }
    groupbar(grp, &bark);

    // ================= Phase C : mem update + rc + rw + reads + out =================
    if (slot < 4){
      const int b = grp + 8*slot;
      for (int k=tid;k<Nn;k+=NTHR) sh.c.ww[k] = S_ww[b][k];
      if (tid < WDn){
        sh.c.er[tid]  = sigm(S_itf[b][OFF_ERASE+tid]);
        sh.c.wvv[tid] = S_itf[b][OFF_WVEC+tid];
      } else if (tid < WDn + Rn*WDn){
        int k = tid - WDn;
        sh.c.rk[k>>6][k&63] = S_itf[b][OFF_RKEY + k];
      } else if (tid < WDn + Rn*WDn + Rn){
        int r = tid - (WDn+Rn*WDn);
        sh.c.beta[r] = oneplusf(S_itf[b][OFF_RSTR + r]);
      } else if (tid < WDn + Rn*WDn + 2*Rn){
        int r = tid - (WDn+Rn*WDn+Rn);
        float m0 = S_itf[b][OFF_MODES + r*3 + 0];
        float m1 = S_itf[b][OFF_MODES + r*3 + 1];
        float m2 = S_itf[b][OFF_MODES + r*3 + 2];
        float mx = fmaxf(m0,fmaxf(m1,m2));
        float e0=expf(m0-mx), e1=expf(m1-mx), e2=expf(m2-mx);
        float si = e0+e1+e2;
        sh.c.modes[r][0]=e0/si; sh.c.modes[r][1]=e1/si; sh.c.modes[r][2]=e2/si;
      }
      for (int k=tid;k<Rn*Nn;k+=NTHR){
        ((float*)sh.c.fw)[k] = ((const float*)S_fw[b])[k];
        float sbw = 0.f;
        #pragma unroll
        for (int ch=0;ch<8;ch++) sbw += ((const float*)S_bwp[b][ch])[k];
        ((float*)sh.c.bw)[k] = sbw;
      }
      __syncthreads();
      if (wvi < 4){
        float kv = sh.c.rk[wvi][lane];
        float s2 = wredsum(kv*kv);
        if (lane==0) sh.c.kn[wvi] = sqrtf(s2);
      }
      __syncthreads();
      // mem erase/write fused with rc dots, 8 tiles of 64 rows via LDS transpose
      for (int tile=0;tile<8;tile++){
        int n0 = tile*64;
        for (int idx=tid; idx<64*64; idx+=NTHR){
          int nn = idx >> 6, w = idx & 63;
          int n = n0 + nn;
          float m = S_mem[b][n][w];
          float wwn = sh.c.ww[n];
          m = m*(1.f - wwn*sh.c.er[w]) + wwn*sh.c.wvv[w];
          S_mem[b][n][w] = m;
          sh.c.tile[nn][w] = m;
        }
        __syncthreads();
        {
          int nn = tid >> 3, q = tid & 7;
          float a0=0.f,a1=0.f,a2=0.f,a3=0.f,nrm=0.f;
          #pragma unroll
          for (int i=0;i<8;i++){
            int w = q*8+i;
            float m = sh.c.tile[nn][w];
            a0 += m*sh.c.rk[0][w]; a1 += m*sh.c.rk[1][w];
            a2 += m*sh.c.rk[2][w]; a3 += m*sh.c.rk[3][w];
            nrm += m*m;
          }
          #pragma unroll
          for (int o=1;o<8;o<<=1){
            a0 += __shfl_xor(a0,o,64); a1 += __shfl_xor(a1,o,64);
            a2 += __shfl_xor(a2,o,64); a3 += __shfl_xor(a3,o,64);
            nrm += __shfl_xor(nrm,o,64);
          }
          if (q==0){
            int n = n0+nn;
            float mn = sqrtf(nrm);
            sh.c.sim[0][n] = sh.c.beta[0]*a0/(sh.c.kn[0]*mn + EPSV);
            sh.c.sim[1][n] = sh.c.beta[1]*a1/(sh.c.kn[1]*mn + EPSV);
            sh.c.sim[2][n] = sh.c.beta[2]*a2/(sh.c.kn[2]*mn + EPSV);
            sh.c.sim[3][n] = sh.c.beta[3]*a3/(sh.c.kn[3]*mn + EPSV);
          }
        }
        __syncthreads();
      }
      // per-head softmax + rw
      for (int r=0;r<Rn;r++){
        float v = sh.c.sim[r][tid];
        float mx = bredmax(v, sh.c.red);
        float e = expf(v - mx);
        float ssum = bredsum(e, sh.c.red);
        float rc = e/ssum;
        float rwv = sh.c.modes[r][2]*rc + sh.c.modes[r][1]*sh.c.fw[r][tid]
                  + sh.c.modes[r][0]*sh.c.bw[r][tid];
        S_rw[b][r][tid] = rwv;
        sh.c.sim[r][tid] = rwv;   // sim now holds rw
      }
      __syncthreads();
      // reads = rw @ mem
      {
        float a0=0.f,a1=0.f,a2=0.f,a3=0.f;
        for (int nn=0;nn<64;nn++){
          int n = wvi*64+nn;
          float m = S_mem[b][n][lane];
          a0 += sh.c.sim[0][n]*m; a1 += sh.c.sim[1][n]*m;
          a2 += sh.c.sim[2][n]*m; a3 += sh.c.sim[3][n]*m;
        }
        sh.c.part[wvi][0][lane]=a0; sh.c.part[wvi][1][lane]=a1;
        sh.c.part[wvi][2][lane]=a2; sh.c.part[wvi][3][lane]=a3;
      }
      __syncthreads();
      if (tid < 256){
        int r = tid>>6, w = tid&63;
        float sv = 0.f;
        #pragma unroll
        for (int v=0;v<8;v++) sv += sh.c.part[v][r][w];
        S_reads[b][r][w] = sv;
        sh.c.vin[256+tid] = sv;
        sh.c.vin[tid] = S_h[b][tid];
      }
      __syncthreads();
      if (tid < 256){
        int q = tid>>6, o = tid&63;
        float sacc = 0.f;
        for (int k2=q*128;k2<q*128+128;k2++) sacc += sh.c.vin[k2]*W_out[(size_t)k2*OUTn + o];
        sh.c.part[q][0][o] = sacc;
      }
      __syncthreads();
      if (tid < 64){
        float sv = b_out[tid] + sh.c.part[0][0][tid] + sh.c.part[1][0][tid]
                 + sh.c.part[2][0][tid] + sh.c.part[3][0][tid];
        outp[((size_t)t*Bn + b)*OUTn + tid] = clipv(sv);
      }
    }
    groupbar(grp, &bark);
  }
}

extern "C" void kernel_launch(void* const* d_in, const int* in_sizes, int n_in,
                              void* d_out, int out_size, void* d_ws, size_t ws_size,
                              hipStream_t stream){
  (void)in_sizes; (void)n_in; (void)d_ws; (void)ws_size; (void)out_size;
  const float* xin = (const float*)d_in[0];
  const float* Wx  = (const float*)d_in[1];
  const float* Wh  = (const float*)d_in[2];
  const float* bl  = (const float*)d_in[3];
  const float* Wif = (const float*)d_in[4];
  const float* bif = (const float*)d_in[5];
  const float* Wo  = (const float*)d_in[6];
  const float* bo  = (const float*)d_in[7];
  hipLaunchKernelGGL(dnc_init_kernel, dim3(1), dim3(512), 0, stream);
  hipLaunchKernelGGL(dnc_main_kernel, dim3(NBLK), dim3(NTHR), 0, stream,
                     xin, Wx, Wh, bl, Wif, bif, Wo, bo, (float*)d_out);
}

// Round 2
// 11828.595 us; speedup vs baseline: 7.1180x; 7.1180x over previous
//
#include <hip/hip_runtime.h>
#include <math.h>

#define Tn 64
#define Bn 32
#define INn 64
#define Nn 512
#define WDn 64
#define Rn 4
#define Hn 256
#define G4H 1024
#define OUTn 64
#define IFn 471
#define CTRLn 320
#define KTOT 576
#define CLIPV 20.0f
#define EPSV 1e-6f

#define OFF_RKEY 0
#define OFF_RSTR 256
#define OFF_WKEY 260
#define OFF_WSTR 324
#define OFF_ERASE 325
#define OFF_WVEC 389
#define OFF_FREE 453
#define OFF_AG 457
#define OFF_WG 458
#define OFF_MODES 459

// ---------------- persistent device state (double-buffered where needed) ----
__device__ float S_h[2][Bn][Hn];
__device__ float S_c[2][Bn][Hn];
__device__ float S_mem[Bn][Nn][WDn];
__device__ float S_rw[Bn][Rn][Nn];
__device__ float S_ww[2][Bn][Nn];
__device__ float S_link[Bn][Nn][Nn];          // 33.5 MB
__device__ float S_prec[2][Bn][Nn];
__device__ float S_usage[2][Bn][Nn];
__device__ float S_reads[Bn][Rn][WDn];
__device__ float S_itf[Bn][IFn];
__device__ float S_fw[Bn][Rn][Nn];
__device__ float S_bwp[Bn][8][Rn][Nn];        // per-chunk bw partials (deterministic)
__device__ float S_sumww[Bn];

// ---------------- helpers ----------------
__device__ __forceinline__ float sigm(float x){ return 1.f/(1.f+expf(-x)); }
__device__ __forceinline__ float clipv(float x){ return fminf(fmaxf(x,-CLIPV),CLIPV); }
__device__ __forceinline__ float oneplusf(float x){
  float sp = (x > 0.f) ? (x + log1pf(expf(-x))) : log1pf(expf(x));
  return 1.f + sp;
}
__device__ __forceinline__ float wredsum(float v){
  #pragma unroll
  for (int o=32;o>0;o>>=1) v += __shfl_xor(v,o,64);
  return v;
}
__device__ __forceinline__ float bredsum(float v, volatile float* scr, int nw){
  v = wredsum(v);
  if ((threadIdx.x & 63) == 0) scr[threadIdx.x >> 6] = v;
  __syncthreads();
  float s = scr[0];
  for (int i=1;i<nw;i++) s += scr[i];
  __syncthreads();
  return s;
}
__device__ __forceinline__ float bredmax(float v, volatile float* scr, int nw){
  #pragma unroll
  for (int o=32;o>0;o>>=1) v = fmaxf(v,__shfl_xor(v,o,64));
  if ((threadIdx.x & 63) == 0) scr[threadIdx.x >> 6] = v;
  __syncthreads();
  float m = scr[0];
  for (int i=1;i<nw;i++) m = fmaxf(m, scr[i]);
  __syncthreads();
  return m;
}

// ================= init: zero persistent state =================
extern "C" __global__ void __launch_bounds__(256)
k_init(){
  size_t g = (size_t)blockIdx.x*256 + threadIdx.x;
  size_t stride = (size_t)gridDim.x*256;
  float* lk = &S_link[0][0][0];
  for (size_t i=g; i<(size_t)Bn*Nn*Nn; i+=stride) lk[i]=0.f;
  float* mm = &S_mem[0][0][0];
  for (size_t i=g; i<(size_t)Bn*Nn*WDn; i+=stride) mm[i]=0.f;
  float* rr = &S_rw[0][0][0];
  for (size_t i=g; i<(size_t)Bn*Rn*Nn; i+=stride) rr[i]=0.f;
  float* rd = &S_reads[0][0][0];
  for (size_t i=g; i<(size_t)Bn*Rn*WDn; i+=stride) rd[i]=0.f;
  for (size_t i=g; i<(size_t)Bn*Nn; i+=stride){
    S_ww[0][0][i]=0.f; S_prec[0][0][i]=0.f; S_usage[0][0][i]=0.f;
  }
  for (size_t i=g; i<(size_t)Bn*Hn; i+=stride){
    S_h[0][0][i]=0.f; S_c[0][0][i]=0.f;
  }
}

// ================= k_gates: batched LSTM (all batches) =================
// grid 32 blocks (8 h-values each) x 256 threads (8 hs x 32 b)
extern "C" __global__ void __launch_bounds__(256)
k_gates(int t, const float* __restrict__ xin,
        const float* __restrict__ Wx, const float* __restrict__ Wh,
        const float* __restrict__ b_lstm){
  __shared__ float ctrlh[Bn][KTOT+1];   // [b][k], pad -> conflict-free
  const int tid = threadIdx.x;
  const int p = t&1, q = p^1;
  // stage [x_t, reads_prev, h_prev] for all batches
  for (int b2=0; b2<Bn; ++b2){
    for (int k=tid; k<KTOT; k+=256){
      float v;
      if (k < INn)        v = xin[((size_t)t*Bn + b2)*INn + k];
      else if (k < CTRLn) v = ((const float*)S_reads[b2])[k-INn];
      else                v = S_h[p][b2][k-CTRLn];
      ctrlh[b2][k] = v;
    }
  }
  __syncthreads();
  const int hs = tid >> 5, b = tid & 31;
  const int h = blockIdx.x*8 + hs;
  float a0=b_lstm[h], a1=b_lstm[Hn+h], a2=b_lstm[2*Hn+h], a3=b_lstm[3*Hn+h];
  for (int k=0;k<CTRLn;k++){
    float cv = ctrlh[b][k];
    const float* w = Wx + (size_t)k*G4H;
    a0 += cv*w[h]; a1 += cv*w[Hn+h]; a2 += cv*w[2*Hn+h]; a3 += cv*w[3*Hn+h];
  }
  for (int k=0;k<Hn;k++){
    float cv = ctrlh[b][CTRLn+k];
    const float* w = Wh + (size_t)k*G4H;
    a0 += cv*w[h]; a1 += cv*w[Hn+h]; a2 += cv*w[2*Hn+h]; a3 += cv*w[3*Hn+h];
  }
  float cold = S_c[p][b][h];
  float cn = sigm(a1)*cold + sigm(a0)*tanhf(a2);
  float hn = sigm(a3)*tanhf(cn);
  S_c[q][b][h] = clipv(cn);
  S_h[q][b][h] = clipv(hn);
}

// ================= k_itf: per-batch interface + usage + alloc + wc + ww ====
// grid 32 blocks x 512 threads
struct ShI {
  float hc[Hn];
  float itf[IFn];
  unsigned long long keys[Nn];
  float alloc[Nn];
  float sim[Nn];
  float wkey[WDn];
  float red[8];
};
extern "C" __global__ void __launch_bounds__(512)
k_itf(int t, const float* __restrict__ W_if, const float* __restrict__ b_if){
  __shared__ ShI sh;
  const int tid = threadIdx.x;
  const int lane = tid & 63, wvi = tid >> 6;
  const int b = blockIdx.x;
  const int p = t&1, q = p^1;
  if (tid < Hn) sh.hc[tid] = S_h[q][b][tid];
  __syncthreads();
  if (tid < IFn){
    float acc = b_if[tid];
    for (int k=0;k<Hn;k++) acc += sh.hc[k]*W_if[(size_t)k*IFn + tid];
    sh.itf[tid] = acc;
    S_itf[b][tid] = acc;
  }
  __syncthreads();
  // usage update + packed stable-sort key
  {
    float fg0=sigm(sh.itf[OFF_FREE+0]), fg1=sigm(sh.itf[OFF_FREE+1]);
    float fg2=sigm(sh.itf[OFF_FREE+2]), fg3=sigm(sh.itf[OFF_FREE+3]);
    int n = tid;
    float uu = S_usage[p][b][n], wwp = S_ww[p][b][n];
    float u = uu + (1.f-uu)*wwp;
    float psi = (1.f - fg0*S_rw[b][0][n])*(1.f - fg1*S_rw[b][1][n])
              * (1.f - fg2*S_rw[b][2][n])*(1.f - fg3*S_rw[b][3][n]);
    float un = u*psi;
    S_usage[q][b][n] = un;
    float v = EPSV + (1.f-EPSV)*un;   // > 0 always
    sh.keys[n] = ((unsigned long long)__float_as_uint(v) << 32) | (unsigned)n;
  }
  __syncthreads();
  // sort-free allocation: a_i = (1-u_i) * prod_{key_j < key_i} u_j
  {
    unsigned long long myk = sh.keys[tid];
    float prod = 1.f;
    for (int j=0;j<Nn;j++){
      unsigned long long kj = sh.keys[j];
      float uj = __uint_as_float((unsigned)(kj>>32));
      prod *= (kj < myk) ? uj : 1.f;
    }
    float myu = __uint_as_float((unsigned)(myk>>32));
    sh.alloc[tid] = (1.f - myu)*prod;
  }
  if (tid < WDn) sh.wkey[tid] = sh.itf[OFF_WKEY+tid];
  __syncthreads();
  // write content sims (wave per 64 rows)
  {
    float kv = sh.wkey[lane];
    float kn = sqrtf(wredsum(kv*kv));
    float beta = oneplusf(sh.itf[OFF_WSTR]);
    for (int nn=0;nn<64;nn++){
      int n = wvi*64+nn;
      float m = S_mem[b][n][lane];
      float dot = wredsum(m*kv);
      float nr  = wredsum(m*m);
      if (lane==0) sh.sim[n] = beta * dot / (kn*sqrtf(nr) + EPSV);
    }
  }
  __syncthreads();
  // softmax over N
  {
    float v = sh.sim[tid];
    float mx = bredmax(v, sh.red, 8);
    float e = expf(v - mx);
    float ssum = bredsum(e, sh.red, 8);
    sh.sim[tid] = e/ssum;
  }
  __syncthreads();
  // ww + sum(ww)
  {
    float ag = sigm(sh.itf[OFF_AG]);
    float wg = sigm(sh.itf[OFF_WG]);
    float wwv = wg*(ag*sh.alloc[tid] + (1.f-ag)*sh.sim[tid]);
    S_ww[q][b][tid] = wwv;
    float ssum = bredsum(wwv, sh.red, 8);
    if (tid==0) S_sumww[b] = ssum;
  }
}

// ================= k_link: link decay/write + fw/bw + prec =================
// grid 256 blocks (8 row-chunks x 32 batches) x 512 threads
struct ShL {
  float ww[Nn];
  float prec[Nn];
  float rw[Rn][Nn];
  float bwp4[4][Rn][Nn];
};
extern "C" __global__ void __launch_bounds__(512)
k_link(int t){
  __shared__ ShL sh;
  const int tid = threadIdx.x;
  const int lane = tid & 63, wvi = tid >> 6;
  const int b = blockIdx.x >> 3;
  const int ch = blockIdx.x & 7;
  const int i0 = ch*64;
  const int p = t&1, q = p^1;
  sh.ww[tid]   = S_ww[q][b][tid];
  sh.prec[tid] = S_prec[p][b][tid];
  for (int k=tid;k<Rn*Nn;k+=512) ((float*)sh.rw)[k] = ((const float*)S_rw[b])[k];
  __syncthreads();
  float sumww = S_sumww[b];
  float wj[8], pj[8], rj0[8], rj1[8], rj2[8], rj3[8];
  #pragma unroll
  for (int jj=0;jj<8;jj++){
    int j = jj*64+lane;
    wj[jj]=sh.ww[j]; pj[jj]=sh.prec[j];
    rj0[jj]=sh.rw[0][j]; rj1[jj]=sh.rw[1][j]; rj2[jj]=sh.rw[2][j]; rj3[jj]=sh.rw[3][j];
  }
  float b0[8]={0,0,0,0,0,0,0,0}, b1[8]={0,0,0,0,0,0,0,0};
  float b2[8]={0,0,0,0,0,0,0,0}, b3[8]={0,0,0,0,0,0,0,0};
  for (int rr=0;rr<8;rr++){
    int i = i0 + wvi*8 + rr;
    float wi = sh.ww[i];
    float ci = 1.f - wi;
    float ri0=sh.rw[0][i], ri1=sh.rw[1][i], ri2=sh.rw[2][i], ri3=sh.rw[3][i];
    float f0=0.f,f1=0.f,f2=0.f,f3=0.f;
    float* lrow = &S_link[b][i][0];
    #pragma unroll
    for (int jj=0;jj<8;jj++){
      int j = jj*64+lane;
      float L = lrow[j];
      float Ln = (ci - wj[jj])*L + wi*pj[jj];
      Ln = (j==i) ? 0.f : Ln;
      lrow[j] = Ln;
      f0 += Ln*rj0[jj]; f1 += Ln*rj1[jj]; f2 += Ln*rj2[jj]; f3 += Ln*rj3[jj];
      b0[jj] += Ln*ri0; b1[jj] += Ln*ri1; b2[jj] += Ln*ri2; b3[jj] += Ln*ri3;
    }
    f0=wredsum(f0); f1=wredsum(f1); f2=wredsum(f2); f3=wredsum(f3);
    if (lane==0){ S_fw[b][0][i]=f0; S_fw[b][1][i]=f1; S_fw[b][2][i]=f2; S_fw[b][3][i]=f3; }
  }
  // deterministic cross-wave bw reduce
  if (wvi < 4){
    #pragma unroll
    for (int jj=0;jj<8;jj++){
      int j = jj*64+lane;
      sh.bwp4[wvi][0][j]=b0[jj]; sh.bwp4[wvi][1][j]=b1[jj];
      sh.bwp4[wvi][2][j]=b2[jj]; sh.bwp4[wvi][3][j]=b3[jj];
    }
  }
  __syncthreads();
  if (wvi >= 4){
    int v = wvi-4;
    #pragma unroll
    for (int jj=0;jj<8;jj++){
      int j = jj*64+lane;
      sh.bwp4[v][0][j]+=b0[jj]; sh.bwp4[v][1][j]+=b1[jj];
      sh.bwp4[v][2][j]+=b2[jj]; sh.bwp4[v][3][j]+=b3[jj];
    }
  }
  __syncthreads();
  for (int k=tid;k<Rn*Nn;k+=512){
    float s = ((float*)sh.bwp4[0])[k] + ((float*)sh.bwp4[1])[k]
            + ((float*)sh.bwp4[2])[k] + ((float*)sh.bwp4[3])[k];
    ((float*)S_bwp[b][ch])[k] = s;
  }
  if (tid < 64){
    int j = i0 + tid;
    S_prec[q][b][j] = (1.f - sumww)*sh.prec[j] + sh.ww[j];
  }
}

// ================= k_read: mem update + rc + rw + reads + out ==============
// grid 32 blocks x 512 threads
struct ShC {
  float ww[Nn];
  float er[WDn];
  float wvv[WDn];
  float rk[Rn][WDn];
  float beta[Rn];
  float kn[Rn];
  float modes[Rn][4];
  float fw[Rn][Nn];
  float bw[Rn][Nn];
  float sim[Rn][Nn];
  float tile[64][65];
  float part[8][Rn][WDn];
  float vin[512];
  float red[8];
};
extern "C" __global__ void __launch_bounds__(512)
k_read(int t, const float* __restrict__ W_out, const float* __restrict__ b_out,
       float* __restrict__ outp){
  __shared__ ShC sh;
  const int tid = threadIdx.x;
  const int lane = tid & 63, wvi = tid >> 6;
  const int b = blockIdx.x;
  const int q = (t&1)^1;
  for (int k=tid;k<Nn;k+=512) sh.ww[k] = S_ww[q][b][k];
  if (tid < WDn){
    sh.er[tid]  = sigm(S_itf[b][OFF_ERASE+tid]);
    sh.wvv[tid] = S_itf[b][OFF_WVEC+tid];
  } else if (tid < WDn + Rn*WDn){
    int k = tid - WDn;
    sh.rk[k>>6][k&63] = S_itf[b][OFF_RKEY + k];
  } else if (tid < WDn + Rn*WDn + Rn){
    int r = tid - (WDn+Rn*WDn);
    sh.beta[r] = oneplusf(S_itf[b][OFF_RSTR + r]);
  } else if (tid < WDn + Rn*WDn + 2*Rn){
    int r = tid - (WDn+Rn*WDn+Rn);
    float m0 = S_itf[b][OFF_MODES + r*3 + 0];
    float m1 = S_itf[b][OFF_MODES + r*3 + 1];
    float m2 = S_itf[b][OFF_MODES + r*3 + 2];
    float mx = fmaxf(m0,fmaxf(m1,m2));
    float e0=expf(m0-mx), e1=expf(m1-mx), e2=expf(m2-mx);
    float si = e0+e1+e2;
    sh.modes[r][0]=e0/si; sh.modes[r][1]=e1/si; sh.modes[r][2]=e2/si;
  }
  for (int k=tid;k<Rn*Nn;k+=512){
    ((float*)sh.fw)[k] = ((const float*)S_fw[b])[k];
    float sbw = 0.f;
    #pragma unroll
    for (int ch=0;ch<8;ch++) sbw += ((const float*)S_bwp[b][ch])[k];
    ((float*)sh.bw)[k] = sbw;
  }
  __syncthreads();
  if (wvi < 4){
    float kv = sh.rk[wvi][lane];
    float s2 = wredsum(kv*kv);
    if (lane==0) sh.kn[wvi] = sqrtf(s2);
  }
  __syncthreads();
  // mem erase/write fused with rc dots (LDS-transposed tiles)
  for (int tile=0;tile<8;tile++){
    int n0 = tile*64;
    for (int idx=tid; idx<64*64; idx+=512){
      int nn = idx >> 6, w = idx & 63;
      int n = n0 + nn;
      float m = S_mem[b][n][w];
      float wwn = sh.ww[n];
      m = m*(1.f - wwn*sh.er[w]) + wwn*sh.wvv[w];
      S_mem[b][n][w] = m;
      sh.tile[nn][w] = m;
    }
    __syncthreads();
    {
      int nn = tid >> 3, qq = tid & 7;
      float a0=0.f,a1=0.f,a2=0.f,a3=0.f,nrm=0.f;
      #pragma unroll
      for (int i=0;i<8;i++){
        int w = qq*8+i;
        float m = sh.tile[nn][w];
        a0 += m*sh.rk[0][w]; a1 += m*sh.rk[1][w];
        a2 += m*sh.rk[2][w]; a3 += m*sh.rk[3][w];
        nrm += m*m;
      }
      #pragma unroll
      for (int o=1;o<8;o<<=1){
        a0 += __shfl_xor(a0,o,64); a1 += __shfl_xor(a1,o,64);
        a2 += __shfl_xor(a2,o,64); a3 += __shfl_xor(a3,o,64);
        nrm += __shfl_xor(nrm,o,64);
      }
      if (qq==0){
        int n = n0+nn;
        float mn = sqrtf(nrm);
        sh.sim[0][n] = sh.beta[0]*a0/(sh.kn[0]*mn + EPSV);
        sh.sim[1][n] = sh.beta[1]*a1/(sh.kn[1]*mn + EPSV);
        sh.sim[2][n] = sh.beta[2]*a2/(sh.kn[2]*mn + EPSV);
        sh.sim[3][n] = sh.beta[3]*a3/(sh.kn[3]*mn + EPSV);
      }
    }
    __syncthreads();
  }
  // per-head softmax + rw
  for (int r=0;r<Rn;r++){
    float v = sh.sim[r][tid];
    float mx = bredmax(v, sh.red, 8);
    float e = expf(v - mx);
    float ssum = bredsum(e, sh.red, 8);
    float rc = e/ssum;
    float rwv = sh.modes[r][2]*rc + sh.modes[r][1]*sh.fw[r][tid]
              + sh.modes[r][0]*sh.bw[r][tid];
    S_rw[b][r][tid] = rwv;
    sh.sim[r][tid] = rwv;   // sim now holds rw
  }
  __syncthreads();
  // reads = rw @ mem
  {
    float a0=0.f,a1=0.f,a2=0.f,a3=0.f;
    for (int nn=0;nn<64;nn++){
      int n = wvi*64+nn;
      float m = S_mem[b][n][lane];
      a0 += sh.sim[0][n]*m; a1 += sh.sim[1][n]*m;
      a2 += sh.sim[2][n]*m; a3 += sh.sim[3][n]*m;
    }
    sh.part[wvi][0][lane]=a0; sh.part[wvi][1][lane]=a1;
    sh.part[wvi][2][lane]=a2; sh.part[wvi][3][lane]=a3;
  }
  __syncthreads();
  if (tid < 256){
    int r = tid>>6, w = tid&63;
    float sv = 0.f;
    #pragma unroll
    for (int v=0;v<8;v++) sv += sh.part[v][r][w];
    S_reads[b][r][w] = sv;
    sh.vin[256+tid] = sv;
    sh.vin[tid] = S_h[q][b][tid];
  }
  __syncthreads();
  if (tid < 256){
    int qq = tid>>6, o = tid&63;
    float sacc = 0.f;
    for (int k2=qq*128;k2<qq*128+128;k2++) sacc += sh.vin[k2]*W_out[(size_t)k2*OUTn + o];
    sh.part[qq][0][o] = sacc;
  }
  __syncthreads();
  if (tid < 64){
    float sv = b_out[tid] + sh.part[0][0][tid] + sh.part[1][0][tid]
             + sh.part[2][0][tid] + sh.part[3][0][tid];
    outp[((size_t)t*Bn + b)*OUTn + tid] = clipv(sv);
  }
}

extern "C" void kernel_launch(void* const* d_in, const int* in_sizes, int n_in,
                              void* d_out, int out_size, void* d_ws, size_t ws_size,
                              hipStream_t stream){
  (void)in_sizes; (void)n_in; (void)d_ws; (void)ws_size; (void)out_size;
  const float* xin = (const float*)d_in[0];
  const float* Wx  = (const float*)d_in[1];
  const float* Wh  = (const float*)d_in[2];
  const float* bl  = (const float*)d_in[3];
  const float* Wif = (const float*)d_in[4];
  const float* bif = (const float*)d_in[5];
  const float* Wo  = (const float*)d_in[6];
  const float* bo  = (const float*)d_in[7];
  hipLaunchKernelGGL(k_init, dim3(1024), dim3(256), 0, stream);
  for (int t=0; t<Tn; ++t){
    hipLaunchKernelGGL(k_gates, dim3(32), dim3(256), 0, stream, t, xin, Wx, Wh, bl);
    hipLaunchKernelGGL(k_itf,   dim3(32), dim3(512), 0, stream, t, Wif, bif);
    hipLaunchKernelGGL(k_link,  dim3(256), dim3(512), 0, stream, t);
    hipLaunchKernelGGL(k_read,  dim3(32), dim3(512), 0, stream, t, Wo, bo, (float*)d_out);
  }
}